// Round 4
// baseline (500.084 us; speedup 1.0000x reference)
//
#include <hip/hip_runtime.h>

#define WAVE 64
#define PAD 16   // one counter per 64B line

// ---------------- degree count (padded counters: no line false-sharing) ----------
__global__ void k_deg(const int* __restrict__ eu, const int* __restrict__ ei,
                      int nE, int nU, int* __restrict__ cnt_p) {
    int e = blockIdx.x * blockDim.x + threadIdx.x;
    if (e < nE) {
        atomicAdd(&cnt_p[(size_t)eu[e] * PAD], 1);
        atomicAdd(&cnt_p[(size_t)(nU + ei[e]) * PAD], 1);
    }
}

// ---------------- compact counts + inv sqrt ----------------
__global__ void k_inv(const int* __restrict__ cnt_p, int* __restrict__ cnt,
                      float* __restrict__ inv, int N) {
    int n = blockIdx.x * blockDim.x + threadIdx.x;
    if (n < N) {
        int c = cnt_p[(size_t)n * PAD];
        cnt[n] = c;
        inv[n] = (c > 0) ? (1.0f / sqrtf((float)c)) : 0.0f;
    }
}

// ---------------- scan phase A: per-block sums (block=256) ----------------
__global__ void k_blocksum(const int* __restrict__ cnt, int N, int* __restrict__ bsum) {
    int i = blockIdx.x * 256 + threadIdx.x;
    int v = (i < N) ? cnt[i] : 0;
    #pragma unroll
    for (int o = 32; o > 0; o >>= 1) v += __shfl_down(v, o, WAVE);
    __shared__ int ws[4];
    if ((threadIdx.x & 63) == 0) ws[threadIdx.x >> 6] = v;
    __syncthreads();
    if (threadIdx.x == 0) bsum[blockIdx.x] = ws[0] + ws[1] + ws[2] + ws[3];
}

// ---------------- scan phase B: single-block exclusive scan of block sums ----------------
__global__ void k_scanbsum(int* __restrict__ bsum, int nB) {
    __shared__ int s[1024];
    int t = threadIdx.x;
    int v = (t < nB) ? bsum[t] : 0;
    s[t] = v;
    __syncthreads();
    for (int o = 1; o < 1024; o <<= 1) {
        int x = (t >= o) ? s[t - o] : 0;
        __syncthreads();
        s[t] += x;
        __syncthreads();
    }
    if (t < nB) bsum[t] = s[t] - v;  // exclusive
}

// ---------------- scan phase C: final positions -> row_ptr & padded cursor --------
__global__ void k_scanfinal(const int* __restrict__ cnt, const int* __restrict__ bsum,
                            int N, int* __restrict__ row_ptr, int* __restrict__ cursor_p) {
    int i = blockIdx.x * 256 + threadIdx.x;
    int v = (i < N) ? cnt[i] : 0;
    int lane = threadIdx.x & 63, wid = threadIdx.x >> 6;
    int inc = v;
    #pragma unroll
    for (int o = 1; o < WAVE; o <<= 1) {
        int x = __shfl_up(inc, o, WAVE);
        if (lane >= o) inc += x;
    }
    __shared__ int wsum[4];
    if (lane == 63) wsum[wid] = inc;
    __syncthreads();
    int woff = 0;
    for (int w2 = 0; w2 < wid; w2++) woff += wsum[w2];
    int excl = inc - v + woff + bsum[blockIdx.x];
    if (i < N) { row_ptr[i] = excl; cursor_p[(size_t)i * PAD] = excl; }
    if (i == N - 1) row_ptr[N] = excl + v;
}

// ---------------- CSR scatter: padded cursors + nontemporal col stores ------------
__global__ void k_scatter(const int* __restrict__ eu, const int* __restrict__ ei,
                          int nE, int nU, int* __restrict__ cursor_p,
                          int* __restrict__ col) {
    int e = blockIdx.x * blockDim.x + threadIdx.x;
    if (e >= nE) return;
    int u = eu[e];
    int v = nU + ei[e];
    int p1 = atomicAdd(&cursor_p[(size_t)v * PAD], 1);
    int p2 = atomicAdd(&cursor_p[(size_t)u * PAD], 1);
    __builtin_nontemporal_store(u, &col[p1]);
    __builtin_nontemporal_store(v, &col[p2]);
}

// ---------------- z0 = inv .* concat(user_emb, item_emb), vectorized ----------------
__global__ void k_initz(const float4* __restrict__ ue, const float4* __restrict__ ie,
                        const float* __restrict__ inv,
                        int nU4, int nTot4, float4* __restrict__ z) {
    int i = blockIdx.x * blockDim.x + threadIdx.x;
    if (i >= nTot4) return;
    float4 v = (i < nU4) ? ue[i] : ie[i - nU4];
    float s = inv[i >> 4];
    v.x *= s; v.y *= s; v.z *= s; v.w *= s;
    z[i] = v;
}

// ---------------- layer-0 batch accumulate: read x0 straight from inputs ----------
__global__ void k_bacc0(const int* __restrict__ users, const int* __restrict__ items,
                        int B, const float* __restrict__ ue, const float* __restrict__ ie,
                        float* __restrict__ acc) {
    int b = blockIdx.x * (blockDim.x >> 6) + (threadIdx.x >> 6);
    int lane = threadIdx.x & 63;
    if (b >= 2 * B) return;
    const float* src = (b < B) ? (ue + (size_t)users[b] * 64)
                               : (ie + (size_t)items[b - B] * 64);
    acc[(size_t)b * 64 + lane] = src[lane];
}

// ---------------- layer-l batch accumulate: x_l = sqrt(deg) * z_l at batch rows ----
__global__ void k_baccl(const int* __restrict__ users, const int* __restrict__ items,
                        int B, int nU, const int* __restrict__ cnt,
                        const float* __restrict__ z, float* __restrict__ acc) {
    int b = blockIdx.x * (blockDim.x >> 6) + (threadIdx.x >> 6);
    int lane = threadIdx.x & 63;
    if (b >= 2 * B) return;
    int row = (b < B) ? users[b] : (nU + items[b - B]);
    float f = sqrtf((float)cnt[row]);
    acc[(size_t)b * 64 + lane] += f * z[(size_t)row * 64 + lane];
}

// ---------------- SPMM: z_out[r] = (1/deg r) * sum_{c in N(r)} z_in[c] -------------
__global__ void k_spmm(const int* __restrict__ row_ptr, const int* __restrict__ col,
                       const float* __restrict__ x, float* __restrict__ y, int N) {
    int row = blockIdx.x * (blockDim.x >> 6) + (threadIdx.x >> 6);
    int lane = threadIdx.x & 63;
    int eidx = lane >> 4;
    int f4   = lane & 15;
    if (row >= N) return;
    int s = row_ptr[row], e = row_ptr[row + 1];
    float4 a0 = make_float4(0.f, 0.f, 0.f, 0.f);
    float4 a1 = make_float4(0.f, 0.f, 0.f, 0.f);
    int j = s + eidx;
    for (; j + 4 < e; j += 8) {
        int c0 = col[j];
        int c1 = col[j + 4];
        float4 v0 = ((const float4*)(x + (size_t)c0 * 64))[f4];
        float4 v1 = ((const float4*)(x + (size_t)c1 * 64))[f4];
        a0.x += v0.x; a0.y += v0.y; a0.z += v0.z; a0.w += v0.w;
        a1.x += v1.x; a1.y += v1.y; a1.z += v1.z; a1.w += v1.w;
    }
    if (j < e) {
        int c = col[j];
        float4 v = ((const float4*)(x + (size_t)c * 64))[f4];
        a0.x += v.x; a0.y += v.y; a0.z += v.z; a0.w += v.w;
    }
    a0.x += a1.x; a0.y += a1.y; a0.z += a1.z; a0.w += a1.w;
    #pragma unroll
    for (int o = 16; o <= 32; o <<= 1) {
        a0.x += __shfl_xor(a0.x, o, WAVE);
        a0.y += __shfl_xor(a0.y, o, WAVE);
        a0.z += __shfl_xor(a0.z, o, WAVE);
        a0.w += __shfl_xor(a0.w, o, WAVE);
    }
    if (eidx == 0) {
        float rdeg = (e > s) ? (1.0f / (float)(e - s)) : 0.0f;
        a0.x *= rdeg; a0.y *= rdeg; a0.z *= rdeg; a0.w *= rdeg;
        ((float4*)(y + (size_t)row * 64))[f4] = a0;
    }
}

// ---------------- final: gamma[b] = dot(acc_u[b], acc_i[b]) / 25 ----------------
__global__ void k_dot(const float* __restrict__ acc, int B, float* __restrict__ out) {
    int b = blockIdx.x * (blockDim.x >> 6) + (threadIdx.x >> 6);
    int lane = threadIdx.x & 63;
    if (b >= B) return;
    float p = acc[(size_t)b * 64 + lane] * acc[(size_t)(b + B) * 64 + lane];
    #pragma unroll
    for (int o = 32; o > 0; o >>= 1) p += __shfl_down(p, o, WAVE);
    if (lane == 0) out[b] = p * (1.0f / 25.0f);
}

extern "C" void kernel_launch(void* const* d_in, const int* in_sizes, int n_in,
                              void* d_out, int out_size, void* d_ws, size_t ws_size,
                              hipStream_t stream) {
    const int*   users = (const int*)d_in[0];
    const int*   items = (const int*)d_in[1];
    const int*   eu    = (const int*)d_in[2];
    const int*   ei    = (const int*)d_in[3];
    const float* ue    = (const float*)d_in[4];
    const float* ie    = (const float*)d_in[5];
    float* out = (float*)d_out;

    const int D  = 64;
    const int B  = in_sizes[0];
    const int nE = in_sizes[2];
    const int nU = in_sizes[4] / D;
    const int nI = in_sizes[5] / D;
    const int N  = nU + nI;

    // ---- carve workspace (256B-aligned chunks) ----
    char* p = (char*)d_ws;
    auto alloc = [&](size_t bytes) -> void* {
        void* r = (void*)p;
        p += (bytes + 255) & ~(size_t)255;
        return r;
    };
    // cnt_p and cursor_p have disjoint lifetimes -> alias the same padded buffer
    int*   cnt_p   = (int*)  alloc((size_t)N * PAD * 4);   // 9.6 MB
    int*   cursor_p = cnt_p;
    int*   cnt     = (int*)  alloc((size_t)N * 4);
    int*   row_ptr = (int*)  alloc((size_t)(N + 1) * 4);
    float* inv     = (float*)alloc((size_t)N * 4);
    int*   col     = (int*)  alloc((size_t)2 * nE * 4);
    float* za      = (float*)alloc((size_t)N * D * 4);
    float* zb      = (float*)alloc((size_t)N * D * 4);
    float* acc     = (float*)alloc((size_t)2 * B * D * 4);
    int*   bsum    = (int*)  alloc(4096);  // up to 1024 block sums

    const int nB = (N + 255) / 256;  // 586 for N=150000; must be <= 1024

    // ---- build CSR (col only; normalization folded into z-space iteration) ----
    hipMemsetAsync(cnt_p, 0, (size_t)N * PAD * 4, stream);
    k_deg<<<(nE + 255) / 256, 256, 0, stream>>>(eu, ei, nE, nU, cnt_p);
    k_inv<<<(N + 255) / 256, 256, 0, stream>>>(cnt_p, cnt, inv, N);
    k_blocksum<<<nB, 256, 0, stream>>>(cnt, N, bsum);
    k_scanbsum<<<1, 1024, 0, stream>>>(bsum, nB);
    k_scanfinal<<<nB, 256, 0, stream>>>(cnt, bsum, N, row_ptr, cursor_p);
    k_scatter<<<(nE + 255) / 256, 256, 0, stream>>>(eu, ei, nE, nU, cursor_p, col);

    // ---- z0 and layer-0 batch accumulate ----
    int nTot4 = N * (D / 4);
    k_initz<<<(nTot4 + 255) / 256, 256, 0, stream>>>(
        (const float4*)ue, (const float4*)ie, inv, nU * (D / 4), nTot4, (float4*)za);
    k_bacc0<<<(2 * B + 3) / 4, 256, 0, stream>>>(users, items, B, ue, ie, acc);

    // ---- 4 propagation layers in z-space: z_{l+1} = D^-1 A z_l ----
    float* zin = za;
    float* zout = zb;
    for (int l = 0; l < 4; l++) {
        k_spmm<<<(N + 3) / 4, 256, 0, stream>>>(row_ptr, col, zin, zout, N);
        k_baccl<<<(2 * B + 3) / 4, 256, 0, stream>>>(users, items, B, nU, cnt, zout, acc);
        float* t = zin; zin = zout; zout = t;
    }

    // ---- final dot ----
    k_dot<<<(B + 3) / 4, 256, 0, stream>>>(acc, B, out);
}

// Round 5
// 440.619 us; speedup vs baseline: 1.1350x; 1.1350x over previous
//
#include <hip/hip_runtime.h>

#define WAVE 64
#define NGRP 8          // per-XCD-ish write groups (blockIdx & 7)
#define BROWS 256       // rows per bucket (bucket = dst >> 8)

// ---------------- phase 0.5: exact per-(group,bucket) histogram ----------------
__global__ void k_hist(const int* __restrict__ eu, const int* __restrict__ ei,
                       int nE, int nU, int nBkt, int* __restrict__ gCnt) {
    __shared__ int h[1024];                    // nBkt <= 1024
    for (int i = threadIdx.x; i < nBkt; i += 256) h[i] = 0;
    __syncthreads();
    int e = blockIdx.x * 256 + threadIdx.x;
    if (e < nE) {
        atomicAdd(&h[eu[e] >> 8], 1);
        atomicAdd(&h[(nU + ei[e]) >> 8], 1);
    }
    __syncthreads();
    int g = blockIdx.x & (NGRP - 1);
    for (int i = threadIdx.x; i < nBkt; i += 256) {
        int c = h[i];
        if (c) atomicAdd(&gCnt[g * nBkt + i], c);
    }
}

// ---------------- scan: fragment bases (g-major) + bucket bases ----------------
__global__ void k_scanb(const int* __restrict__ gCnt, int* __restrict__ gBase,
                        int* __restrict__ gCur, int* __restrict__ bktBase,
                        int* __restrict__ row_ptr, int nBkt, int N, int total) {
    const int M = NGRP * nBkt;                 // 4688
    const int C = (M + 1023) / 1024;           // 5
    __shared__ int part[1024];
    int t = threadIdx.x;
    int base_i = t * C;
    int lsum = 0;
    for (int k = 0; k < C; k++) {
        int i = base_i + k;
        if (i < M) lsum += gCnt[i];
    }
    part[t] = lsum;
    __syncthreads();
    for (int o = 1; o < 1024; o <<= 1) {
        int x = (t >= o) ? part[t - o] : 0;
        __syncthreads();
        part[t] += x;
        __syncthreads();
    }
    int run = part[t] - lsum;                  // exclusive
    for (int k = 0; k < C; k++) {
        int i = base_i + k;
        if (i < M) {
            gBase[i] = run; gCur[i] = run;
            run += gCnt[i];
        }
    }
    __syncthreads();
    // bucket totals then exclusive scan (nBkt <= 1024)
    int bt = 0;
    if (t < nBkt)
        for (int g = 0; g < NGRP; g++) bt += gCnt[g * nBkt + t];
    part[t] = bt;
    __syncthreads();
    for (int o = 1; o < 1024; o <<= 1) {
        int x = (t >= o) ? part[t - o] : 0;
        __syncthreads();
        part[t] += x;
        __syncthreads();
    }
    if (t < nBkt) bktBase[t] = part[t] - bt;
    if (t == 0) { bktBase[nBkt] = total; row_ptr[N] = total; }
}

// ---------------- phase 1: bin (dst,src) pairs into per-(g,bucket) regions ------
// MUST use the same grid/block mapping as k_hist so g matches the histogram.
__global__ void k_bin(const int* __restrict__ eu, const int* __restrict__ ei,
                      int nE, int nU, int nBkt, int* __restrict__ gCur,
                      int2* __restrict__ bins) {
    int e = blockIdx.x * 256 + threadIdx.x;
    if (e >= nE) return;
    int g = blockIdx.x & (NGRP - 1);
    int u = eu[e];
    int v = nU + ei[e];
    int p1 = atomicAdd(&gCur[g * nBkt + (u >> 8)], 1);
    int p2 = atomicAdd(&gCur[g * nBkt + (v >> 8)], 1);
    bins[p1] = make_int2(u, v);
    bins[p2] = make_int2(v, u);
}

// ---------------- phase 2: per-bucket CSR finalize (one block per bucket) -------
// LDS histogram + scan over 256 rows; col writes land in the block's private
// contiguous window -> full-line writebacks, no global atomics.
__global__ void k_csr(const int2* __restrict__ bins, const int* __restrict__ gBase,
                      const int* __restrict__ gCnt, const int* __restrict__ bktBase,
                      int nBkt, int N, int* __restrict__ row_ptr,
                      int* __restrict__ cnt, float* __restrict__ inv,
                      int* __restrict__ col) {
    __shared__ int h[BROWS], s[BROWS], cur[BROWS];
    int b = blockIdx.x;
    int t = threadIdx.x;
    h[t] = 0;
    __syncthreads();
    for (int g = 0; g < NGRP; g++) {
        int base = gBase[g * nBkt + b];
        int n = gCnt[g * nBkt + b];
        for (int i = t; i < n; i += BROWS) {
            int2 p = bins[base + i];
            atomicAdd(&h[p.x & (BROWS - 1)], 1);
        }
    }
    __syncthreads();
    int v = h[t];
    s[t] = v;
    __syncthreads();
    for (int o = 1; o < BROWS; o <<= 1) {
        int x = (t >= o) ? s[t - o] : 0;
        __syncthreads();
        s[t] += x;
        __syncthreads();
    }
    int excl = s[t] - v;
    int cbase = bktBase[b];
    int row = b * BROWS + t;
    if (row < N) {
        row_ptr[row] = cbase + excl;
        cnt[row] = v;
        inv[row] = (v > 0) ? (1.0f / sqrtf((float)v)) : 0.0f;
    }
    cur[t] = excl;
    __syncthreads();
    for (int g = 0; g < NGRP; g++) {
        int base = gBase[g * nBkt + b];
        int n = gCnt[g * nBkt + b];
        for (int i = t; i < n; i += BROWS) {
            int2 p = bins[base + i];
            int pos = cbase + atomicAdd(&cur[p.x & (BROWS - 1)], 1);
            col[pos] = p.y;
        }
    }
}

// ---------------- z0 = inv .* concat(user_emb, item_emb), vectorized ------------
__global__ void k_initz(const float4* __restrict__ ue, const float4* __restrict__ ie,
                        const float* __restrict__ inv,
                        int nU4, int nTot4, float4* __restrict__ z) {
    int i = blockIdx.x * blockDim.x + threadIdx.x;
    if (i >= nTot4) return;
    float4 v = (i < nU4) ? ue[i] : ie[i - nU4];
    float s = inv[i >> 4];
    v.x *= s; v.y *= s; v.z *= s; v.w *= s;
    z[i] = v;
}

// ---------------- layer-0 batch accumulate: read x0 straight from inputs --------
__global__ void k_bacc0(const int* __restrict__ users, const int* __restrict__ items,
                        int B, const float* __restrict__ ue, const float* __restrict__ ie,
                        float* __restrict__ acc) {
    int b = blockIdx.x * (blockDim.x >> 6) + (threadIdx.x >> 6);
    int lane = threadIdx.x & 63;
    if (b >= 2 * B) return;
    const float* src = (b < B) ? (ue + (size_t)users[b] * 64)
                               : (ie + (size_t)items[b - B] * 64);
    acc[(size_t)b * 64 + lane] = src[lane];
}

// ---------------- layer-l batch accumulate: x_l = sqrt(deg) * z_l ---------------
__global__ void k_baccl(const int* __restrict__ users, const int* __restrict__ items,
                        int B, int nU, const int* __restrict__ cnt,
                        const float* __restrict__ z, float* __restrict__ acc) {
    int b = blockIdx.x * (blockDim.x >> 6) + (threadIdx.x >> 6);
    int lane = threadIdx.x & 63;
    if (b >= 2 * B) return;
    int row = (b < B) ? users[b] : (nU + items[b - B]);
    float f = sqrtf((float)cnt[row]);
    acc[(size_t)b * 64 + lane] += f * z[(size_t)row * 64 + lane];
}

// ---------------- SPMM: z_out[r] = (1/deg r) * sum_{c in N(r)} z_in[c] ----------
__global__ void k_spmm(const int* __restrict__ row_ptr, const int* __restrict__ col,
                       const float* __restrict__ x, float* __restrict__ y, int N) {
    int row = blockIdx.x * (blockDim.x >> 6) + (threadIdx.x >> 6);
    int lane = threadIdx.x & 63;
    int eidx = lane >> 4;
    int f4   = lane & 15;
    if (row >= N) return;
    int s = row_ptr[row], e = row_ptr[row + 1];
    float4 a0 = make_float4(0.f, 0.f, 0.f, 0.f);
    float4 a1 = make_float4(0.f, 0.f, 0.f, 0.f);
    int j = s + eidx;
    for (; j + 4 < e; j += 8) {
        int c0 = col[j];
        int c1 = col[j + 4];
        float4 v0 = ((const float4*)(x + (size_t)c0 * 64))[f4];
        float4 v1 = ((const float4*)(x + (size_t)c1 * 64))[f4];
        a0.x += v0.x; a0.y += v0.y; a0.z += v0.z; a0.w += v0.w;
        a1.x += v1.x; a1.y += v1.y; a1.z += v1.z; a1.w += v1.w;
    }
    if (j < e) {
        int c = col[j];
        float4 v = ((const float4*)(x + (size_t)c * 64))[f4];
        a0.x += v.x; a0.y += v.y; a0.z += v.z; a0.w += v.w;
    }
    a0.x += a1.x; a0.y += a1.y; a0.z += a1.z; a0.w += a1.w;
    #pragma unroll
    for (int o = 16; o <= 32; o <<= 1) {
        a0.x += __shfl_xor(a0.x, o, WAVE);
        a0.y += __shfl_xor(a0.y, o, WAVE);
        a0.z += __shfl_xor(a0.z, o, WAVE);
        a0.w += __shfl_xor(a0.w, o, WAVE);
    }
    if (eidx == 0) {
        float rdeg = (e > s) ? (1.0f / (float)(e - s)) : 0.0f;
        a0.x *= rdeg; a0.y *= rdeg; a0.z *= rdeg; a0.w *= rdeg;
        ((float4*)(y + (size_t)row * 64))[f4] = a0;
    }
}

// ---------------- final: gamma[b] = dot(acc_u[b], acc_i[b]) / 25 ----------------
__global__ void k_dot(const float* __restrict__ acc, int B, float* __restrict__ out) {
    int b = blockIdx.x * (blockDim.x >> 6) + (threadIdx.x >> 6);
    int lane = threadIdx.x & 63;
    if (b >= B) return;
    float p = acc[(size_t)b * 64 + lane] * acc[(size_t)(b + B) * 64 + lane];
    #pragma unroll
    for (int o = 32; o > 0; o >>= 1) p += __shfl_down(p, o, WAVE);
    if (lane == 0) out[b] = p * (1.0f / 25.0f);
}

extern "C" void kernel_launch(void* const* d_in, const int* in_sizes, int n_in,
                              void* d_out, int out_size, void* d_ws, size_t ws_size,
                              hipStream_t stream) {
    const int*   users = (const int*)d_in[0];
    const int*   items = (const int*)d_in[1];
    const int*   eu    = (const int*)d_in[2];
    const int*   ei    = (const int*)d_in[3];
    const float* ue    = (const float*)d_in[4];
    const float* ie    = (const float*)d_in[5];
    float* out = (float*)d_out;

    const int D  = 64;
    const int B  = in_sizes[0];
    const int nE = in_sizes[2];
    const int nU = in_sizes[4] / D;
    const int nI = in_sizes[5] / D;
    const int N  = nU + nI;
    const int nBkt = (N + BROWS - 1) / BROWS;   // 586 (<= 1024 required)
    const int total = 2 * nE;

    // ---- carve workspace (256B-aligned chunks) ----
    char* p = (char*)d_ws;
    auto alloc = [&](size_t bytes) -> void* {
        void* r = (void*)p;
        p += (bytes + 255) & ~(size_t)255;
        return r;
    };
    int*   gCnt    = (int*)  alloc((size_t)NGRP * nBkt * 4);
    int*   gBase   = (int*)  alloc((size_t)NGRP * nBkt * 4);
    int*   gCur    = (int*)  alloc((size_t)NGRP * nBkt * 4);
    int*   bktBase = (int*)  alloc((size_t)(nBkt + 1) * 4);
    int2*  bins    = (int2*) alloc((size_t)total * 8);        // 19.2 MB
    int*   col     = (int*)  alloc((size_t)total * 4);        // 9.6 MB
    int*   row_ptr = (int*)  alloc((size_t)(N + 1) * 4);
    int*   cnt     = (int*)  alloc((size_t)N * 4);
    float* inv     = (float*)alloc((size_t)N * 4);
    float* za      = (float*)alloc((size_t)N * D * 4);
    float* zb      = (float*)alloc((size_t)N * D * 4);
    float* acc     = (float*)alloc((size_t)2 * B * D * 4);

    const int nBlkE = (nE + 255) / 256;   // shared by k_hist / k_bin (g mapping)

    // ---- build CSR: binned two-phase, no random-scatter writeback ----
    hipMemsetAsync(gCnt, 0, (size_t)NGRP * nBkt * 4, stream);
    k_hist<<<nBlkE, 256, 0, stream>>>(eu, ei, nE, nU, nBkt, gCnt);
    k_scanb<<<1, 1024, 0, stream>>>(gCnt, gBase, gCur, bktBase, row_ptr, nBkt, N, total);
    k_bin<<<nBlkE, 256, 0, stream>>>(eu, ei, nE, nU, nBkt, gCur, bins);
    k_csr<<<nBkt, BROWS, 0, stream>>>(bins, gBase, gCnt, bktBase, nBkt, N,
                                      row_ptr, cnt, inv, col);

    // ---- z0 and layer-0 batch accumulate ----
    int nTot4 = N * (D / 4);
    k_initz<<<(nTot4 + 255) / 256, 256, 0, stream>>>(
        (const float4*)ue, (const float4*)ie, inv, nU * (D / 4), nTot4, (float4*)za);
    k_bacc0<<<(2 * B + 3) / 4, 256, 0, stream>>>(users, items, B, ue, ie, acc);

    // ---- 4 propagation layers in z-space: z_{l+1} = D^-1 A z_l ----
    float* zin = za;
    float* zout = zb;
    for (int l = 0; l < 4; l++) {
        k_spmm<<<(N + 3) / 4, 256, 0, stream>>>(row_ptr, col, zin, zout, N);
        k_baccl<<<(2 * B + 3) / 4, 256, 0, stream>>>(users, items, B, nU, cnt, zout, acc);
        float* t = zin; zin = zout; zout = t;
    }

    // ---- final dot ----
    k_dot<<<(B + 3) / 4, 256, 0, stream>>>(acc, B, out);
}

// Round 6
// 371.473 us; speedup vs baseline: 1.3462x; 1.1861x over previous
//
#include <hip/hip_runtime.h>

#define WAVE 64
#define BROWS 256        // rows per bucket (bucket = node >> 8)
#define NBKT_MAX 1024
#define CMAX 16          // max per-thread chunk in k_scanBkt (nJ <= 256*CMAX)

// ---------------- phase 1: per-block bucket histogram, coalesced row write ------
__global__ void k_hist(const int* __restrict__ eu, const int* __restrict__ ei,
                       int nE, int nU, int nBkt, int nJg, int* __restrict__ cntBB) {
    __shared__ int h[NBKT_MAX];
    for (int i = threadIdx.x; i < nBkt; i += 256) h[i] = 0;
    __syncthreads();
    int e = blockIdx.x * 256 + threadIdx.x;
    if (e < nE) {
        atomicAdd(&h[eu[e] >> 8], 1);
        atomicAdd(&h[(nU + ei[e]) >> 8], 1);
    }
    __syncthreads();
    int j = (blockIdx.x & 7) * nJg + (blockIdx.x >> 3);   // XCD-affine block order
    int* dst = cntBB + (size_t)j * nBkt;
    for (int i = threadIdx.x; i < nBkt; i += 256) dst[i] = h[i];
}

// ---------------- phase 2a: per-bucket scan over blocks -> fragment bases --------
// grid = nBkt blocks; reads cntBB[j][b] (strided, L2/L3-resident), writes
// baseBB[b][j] (coalesced) and bktTot[b].
__global__ void k_scanBkt(const int* __restrict__ cntBB, int* __restrict__ baseBB,
                          int* __restrict__ bktTot, int nBkt, int nJ) {
    __shared__ int s[256];
    int b = blockIdx.x, t = threadIdx.x;
    int C = (nJ + 255) / 256;
    int vals[CMAX];
    int sum = 0;
    for (int k = 0; k < CMAX; k++) {
        if (k >= C) break;
        int j = t * C + k;
        int v = (j < nJ) ? cntBB[(size_t)j * nBkt + b] : 0;
        vals[k] = v; sum += v;
    }
    s[t] = sum;
    __syncthreads();
    for (int o = 1; o < 256; o <<= 1) {
        int x = (t >= o) ? s[t - o] : 0;
        __syncthreads();
        s[t] += x;
        __syncthreads();
    }
    int run = s[t] - sum;  // exclusive
    for (int k = 0; k < CMAX; k++) {
        if (k >= C) break;
        int j = t * C + k;
        if (j < nJ) { baseBB[(size_t)b * nJ + j] = run; run += vals[k]; }
    }
    if (t == 0) bktTot[b] = s[255];
}

// ---------------- phase 2b: scan bucket totals -> bktBase, row_ptr[N] ------------
__global__ void k_scanTot(const int* __restrict__ bktTot, int* __restrict__ bktBase,
                          int* __restrict__ row_ptr, int nBkt, int N, int total) {
    __shared__ int s[1024];
    int t = threadIdx.x;
    int v = (t < nBkt) ? bktTot[t] : 0;
    s[t] = v;
    __syncthreads();
    for (int o = 1; o < 1024; o <<= 1) {
        int x = (t >= o) ? s[t - o] : 0;
        __syncthreads();
        s[t] += x;
        __syncthreads();
    }
    if (t < nBkt) bktBase[t] = s[t] - v;
    if (t == 0) { bktBase[nBkt] = total; row_ptr[N] = total; }
}

// ---------------- phase 3: bin pairs; LDS atomics only ---------------------------
__global__ void k_bin(const int* __restrict__ eu, const int* __restrict__ ei,
                      int nE, int nU, int nBkt, int nJ, int nJg,
                      const int* __restrict__ baseBB, const int* __restrict__ bktBase,
                      int2* __restrict__ bins) {
    __shared__ int cur[NBKT_MAX];
    int j = (blockIdx.x & 7) * nJg + (blockIdx.x >> 3);
    for (int i = threadIdx.x; i < nBkt; i += 256)
        cur[i] = bktBase[i] + baseBB[(size_t)i * nJ + j];
    __syncthreads();
    int e = blockIdx.x * 256 + threadIdx.x;
    if (e >= nE) return;
    int u = eu[e];
    int v = nU + ei[e];
    int p1 = atomicAdd(&cur[u >> 8], 1);   // LDS atomic
    int p2 = atomicAdd(&cur[v >> 8], 1);
    bins[p1] = make_int2(u, v);            // (dst, src)
    bins[p2] = make_int2(v, u);
}

// ---------------- phase 4: per-bucket CSR finalize (contiguous range) ------------
__global__ void k_csr(const int2* __restrict__ bins, const int* __restrict__ bktBase,
                      int N, int* __restrict__ row_ptr, int* __restrict__ cnt,
                      float* __restrict__ inv, int* __restrict__ col) {
    __shared__ int h[BROWS], s[BROWS], cur[BROWS];
    int b = blockIdx.x, t = threadIdx.x;
    int base = bktBase[b];
    int n = bktBase[b + 1] - base;
    h[t] = 0;
    __syncthreads();
    for (int i = t; i < n; i += BROWS)
        atomicAdd(&h[bins[base + i].x & (BROWS - 1)], 1);
    __syncthreads();
    int v = h[t];
    s[t] = v;
    __syncthreads();
    for (int o = 1; o < BROWS; o <<= 1) {
        int x = (t >= o) ? s[t - o] : 0;
        __syncthreads();
        s[t] += x;
        __syncthreads();
    }
    int excl = s[t] - v;
    int row = b * BROWS + t;
    if (row < N) {
        row_ptr[row] = base + excl;
        cnt[row] = v;
        inv[row] = (v > 0) ? (1.0f / sqrtf((float)v)) : 0.0f;
    }
    cur[t] = excl;
    __syncthreads();
    for (int i = t; i < n; i += BROWS) {
        int2 p = bins[base + i];
        int pos = base + atomicAdd(&cur[p.x & (BROWS - 1)], 1);
        col[pos] = p.y;
    }
}

// ---------------- z0 = inv .* concat(user_emb, item_emb), vectorized ------------
__global__ void k_initz(const float4* __restrict__ ue, const float4* __restrict__ ie,
                        const float* __restrict__ inv,
                        int nU4, int nTot4, float4* __restrict__ z) {
    int i = blockIdx.x * blockDim.x + threadIdx.x;
    if (i >= nTot4) return;
    float4 v = (i < nU4) ? ue[i] : ie[i - nU4];
    float s = inv[i >> 4];
    v.x *= s; v.y *= s; v.z *= s; v.w *= s;
    z[i] = v;
}

// ---------------- layer-0 batch accumulate: read x0 straight from inputs --------
__global__ void k_bacc0(const int* __restrict__ users, const int* __restrict__ items,
                        int B, const float* __restrict__ ue, const float* __restrict__ ie,
                        float* __restrict__ acc) {
    int b = blockIdx.x * (blockDim.x >> 6) + (threadIdx.x >> 6);
    int lane = threadIdx.x & 63;
    if (b >= 2 * B) return;
    const float* src = (b < B) ? (ue + (size_t)users[b] * 64)
                               : (ie + (size_t)items[b - B] * 64);
    acc[(size_t)b * 64 + lane] = src[lane];
}

// ---------------- layer-l batch accumulate: x_l = sqrt(deg) * z_l ---------------
__global__ void k_baccl(const int* __restrict__ users, const int* __restrict__ items,
                        int B, int nU, const int* __restrict__ cnt,
                        const float* __restrict__ z, float* __restrict__ acc) {
    int b = blockIdx.x * (blockDim.x >> 6) + (threadIdx.x >> 6);
    int lane = threadIdx.x & 63;
    if (b >= 2 * B) return;
    int row = (b < B) ? users[b] : (nU + items[b - B]);
    float f = sqrtf((float)cnt[row]);
    acc[(size_t)b * 64 + lane] += f * z[(size_t)row * 64 + lane];
}

// ---------------- SPMM: z_out[r] = (1/deg r) * sum_{c in N(r)} z_in[c] ----------
__global__ void k_spmm(const int* __restrict__ row_ptr, const int* __restrict__ col,
                       const float* __restrict__ x, float* __restrict__ y, int N) {
    int row = blockIdx.x * (blockDim.x >> 6) + (threadIdx.x >> 6);
    int lane = threadIdx.x & 63;
    int eidx = lane >> 4;
    int f4   = lane & 15;
    if (row >= N) return;
    int s = row_ptr[row], e = row_ptr[row + 1];
    float4 a0 = make_float4(0.f, 0.f, 0.f, 0.f);
    float4 a1 = make_float4(0.f, 0.f, 0.f, 0.f);
    int j = s + eidx;
    for (; j + 4 < e; j += 8) {
        int c0 = col[j];
        int c1 = col[j + 4];
        float4 v0 = ((const float4*)(x + (size_t)c0 * 64))[f4];
        float4 v1 = ((const float4*)(x + (size_t)c1 * 64))[f4];
        a0.x += v0.x; a0.y += v0.y; a0.z += v0.z; a0.w += v0.w;
        a1.x += v1.x; a1.y += v1.y; a1.z += v1.z; a1.w += v1.w;
    }
    if (j < e) {
        int c = col[j];
        float4 v = ((const float4*)(x + (size_t)c * 64))[f4];
        a0.x += v.x; a0.y += v.y; a0.z += v.z; a0.w += v.w;
    }
    a0.x += a1.x; a0.y += a1.y; a0.z += a1.z; a0.w += a1.w;
    #pragma unroll
    for (int o = 16; o <= 32; o <<= 1) {
        a0.x += __shfl_xor(a0.x, o, WAVE);
        a0.y += __shfl_xor(a0.y, o, WAVE);
        a0.z += __shfl_xor(a0.z, o, WAVE);
        a0.w += __shfl_xor(a0.w, o, WAVE);
    }
    if (eidx == 0) {
        float rdeg = (e > s) ? (1.0f / (float)(e - s)) : 0.0f;
        a0.x *= rdeg; a0.y *= rdeg; a0.z *= rdeg; a0.w *= rdeg;
        ((float4*)(y + (size_t)row * 64))[f4] = a0;
    }
}

// ---------------- final: gamma[b] = dot(acc_u[b], acc_i[b]) / 25 ----------------
__global__ void k_dot(const float* __restrict__ acc, int B, float* __restrict__ out) {
    int b = blockIdx.x * (blockDim.x >> 6) + (threadIdx.x >> 6);
    int lane = threadIdx.x & 63;
    if (b >= B) return;
    float p = acc[(size_t)b * 64 + lane] * acc[(size_t)(b + B) * 64 + lane];
    #pragma unroll
    for (int o = 32; o > 0; o >>= 1) p += __shfl_down(p, o, WAVE);
    if (lane == 0) out[b] = p * (1.0f / 25.0f);
}

extern "C" void kernel_launch(void* const* d_in, const int* in_sizes, int n_in,
                              void* d_out, int out_size, void* d_ws, size_t ws_size,
                              hipStream_t stream) {
    const int*   users = (const int*)d_in[0];
    const int*   items = (const int*)d_in[1];
    const int*   eu    = (const int*)d_in[2];
    const int*   ei    = (const int*)d_in[3];
    const float* ue    = (const float*)d_in[4];
    const float* ie    = (const float*)d_in[5];
    float* out = (float*)d_out;

    const int D  = 64;
    const int B  = in_sizes[0];
    const int nE = in_sizes[2];
    const int nU = in_sizes[4] / D;
    const int nI = in_sizes[5] / D;
    const int N  = nU + nI;
    const int nBkt = (N + BROWS - 1) / BROWS;   // 586 (<= NBKT_MAX required)
    const int total = 2 * nE;

    const int nBlkE = (nE + 255) / 256;         // 2344
    const int nJg   = (nBlkE + 7) / 8;          // 293
    const int nJ    = 8 * nJg;                  // 2344 (holes memset to 0 below)

    // ---- carve workspace (256B-aligned chunks) ----
    char* p = (char*)d_ws;
    auto alloc = [&](size_t bytes) -> void* {
        void* r = (void*)p;
        p += (bytes + 255) & ~(size_t)255;
        return r;
    };
    int*   cntBB   = (int*)  alloc((size_t)nJ * nBkt * 4);     // 5.5 MB
    int*   baseBB  = (int*)  alloc((size_t)nBkt * nJ * 4);     // 5.5 MB
    int*   bktTot  = (int*)  alloc((size_t)nBkt * 4);
    int*   bktBase = (int*)  alloc((size_t)(nBkt + 1) * 4);
    int2*  bins    = (int2*) alloc((size_t)total * 8);         // 19.2 MB
    int*   col     = (int*)  alloc((size_t)total * 4);         // 9.6 MB
    int*   row_ptr = (int*)  alloc((size_t)(N + 1) * 4);
    int*   cnt     = (int*)  alloc((size_t)N * 4);
    float* inv     = (float*)alloc((size_t)N * 4);
    float* za      = (float*)alloc((size_t)N * D * 4);
    float* zb      = (float*)alloc((size_t)N * D * 4);
    float* acc     = (float*)alloc((size_t)2 * B * D * 4);

    // ---- build CSR: zero global atomics ----
    hipMemsetAsync(cntBB, 0, (size_t)nJ * nBkt * 4, stream);   // covers nJ>nBlkE holes
    k_hist<<<nBlkE, 256, 0, stream>>>(eu, ei, nE, nU, nBkt, nJg, cntBB);
    k_scanBkt<<<nBkt, 256, 0, stream>>>(cntBB, baseBB, bktTot, nBkt, nJ);
    k_scanTot<<<1, 1024, 0, stream>>>(bktTot, bktBase, row_ptr, nBkt, N, total);
    k_bin<<<nBlkE, 256, 0, stream>>>(eu, ei, nE, nU, nBkt, nJ, nJg, baseBB, bktBase, bins);
    k_csr<<<nBkt, BROWS, 0, stream>>>(bins, bktBase, N, row_ptr, cnt, inv, col);

    // ---- z0 and layer-0 batch accumulate ----
    int nTot4 = N * (D / 4);
    k_initz<<<(nTot4 + 255) / 256, 256, 0, stream>>>(
        (const float4*)ue, (const float4*)ie, inv, nU * (D / 4), nTot4, (float4*)za);
    k_bacc0<<<(2 * B + 3) / 4, 256, 0, stream>>>(users, items, B, ue, ie, acc);

    // ---- 4 propagation layers in z-space: z_{l+1} = D^-1 A z_l ----
    float* zin = za;
    float* zout = zb;
    for (int l = 0; l < 4; l++) {
        k_spmm<<<(N + 3) / 4, 256, 0, stream>>>(row_ptr, col, zin, zout, N);
        k_baccl<<<(2 * B + 3) / 4, 256, 0, stream>>>(users, items, B, nU, cnt, zout, acc);
        float* t = zin; zin = zout; zout = t;
    }

    // ---- final dot ----
    k_dot<<<(B + 3) / 4, 256, 0, stream>>>(acc, B, out);
}

// Round 8
// 355.128 us; speedup vs baseline: 1.4082x; 1.0460x over previous
//
#include <hip/hip_runtime.h>

#define WAVE 64
#define BROWS 256        // rows per bucket (bucket = node >> 8)
#define NBKT_MAX 1024
#define CMAX 16          // max per-thread chunk in k_scanBkt (nJ <= 256*CMAX)
#define SRCMASK 0x3FFFF  // 18-bit src field in packed bins entry

// ---------------- phase 1: per-block bucket histogram, coalesced row write ------
__global__ void k_hist(const int* __restrict__ eu, const int* __restrict__ ei,
                       int nE, int nU, int nBkt, int nJg, int* __restrict__ cntBB) {
    __shared__ int h[NBKT_MAX];
    for (int i = threadIdx.x; i < nBkt; i += 256) h[i] = 0;
    __syncthreads();
    int e = blockIdx.x * 256 + threadIdx.x;
    if (e < nE) {
        atomicAdd(&h[eu[e] >> 8], 1);
        atomicAdd(&h[(nU + ei[e]) >> 8], 1);
    }
    __syncthreads();
    int j = (blockIdx.x & 7) * nJg + (blockIdx.x >> 3);   // XCD-affine block order
    int* dst = cntBB + (size_t)j * nBkt;
    for (int i = threadIdx.x; i < nBkt; i += 256) dst[i] = h[i];
}

// ---------------- phase 2a: per-bucket scan over blocks -> fragment bases --------
__global__ void k_scanBkt(const int* __restrict__ cntBB, int* __restrict__ baseBB,
                          int* __restrict__ bktTot, int nBkt, int nJ) {
    __shared__ int s[256];
    int b = blockIdx.x, t = threadIdx.x;
    int C = (nJ + 255) / 256;
    int vals[CMAX];
    int sum = 0;
    for (int k = 0; k < CMAX; k++) {
        if (k >= C) break;
        int j = t * C + k;
        int v = (j < nJ) ? cntBB[(size_t)j * nBkt + b] : 0;
        vals[k] = v; sum += v;
    }
    s[t] = sum;
    __syncthreads();
    for (int o = 1; o < 256; o <<= 1) {
        int x = (t >= o) ? s[t - o] : 0;
        __syncthreads();
        s[t] += x;
        __syncthreads();
    }
    int run = s[t] - sum;  // exclusive
    for (int k = 0; k < CMAX; k++) {
        if (k >= C) break;
        int j = t * C + k;
        if (j < nJ) { baseBB[(size_t)b * nJ + j] = run; run += vals[k]; }
    }
    if (t == 0) bktTot[b] = s[255];
}

// ---------------- phase 2b: scan bucket totals -> bktBase, row_ptr[N] ------------
__global__ void k_scanTot(const int* __restrict__ bktTot, int* __restrict__ bktBase,
                          int* __restrict__ row_ptr, int nBkt, int N, int total) {
    __shared__ int s[1024];
    int t = threadIdx.x;
    int v = (t < nBkt) ? bktTot[t] : 0;
    s[t] = v;
    __syncthreads();
    for (int o = 1; o < 1024; o <<= 1) {
        int x = (t >= o) ? s[t - o] : 0;
        __syncthreads();
        s[t] += x;
        __syncthreads();
    }
    if (t < nBkt) bktBase[t] = s[t] - v;
    if (t == 0) { bktBase[nBkt] = total; row_ptr[N] = total; }
}

// ---------------- phase 3: bin packed entries; LDS atomics only ------------------
// entry = ((dst & 255) << 18) | src   (src < 2^18)
__global__ void k_bin(const int* __restrict__ eu, const int* __restrict__ ei,
                      int nE, int nU, int nBkt, int nJ, int nJg,
                      const int* __restrict__ baseBB, const int* __restrict__ bktBase,
                      int* __restrict__ bins) {
    __shared__ int cur[NBKT_MAX];
    int j = (blockIdx.x & 7) * nJg + (blockIdx.x >> 3);
    for (int i = threadIdx.x; i < nBkt; i += 256)
        cur[i] = bktBase[i] + baseBB[(size_t)i * nJ + j];
    __syncthreads();
    int e = blockIdx.x * 256 + threadIdx.x;
    if (e >= nE) return;
    int u = eu[e];
    int v = nU + ei[e];
    int p1 = atomicAdd(&cur[u >> 8], 1);   // LDS atomic
    int p2 = atomicAdd(&cur[v >> 8], 1);
    __builtin_nontemporal_store(((u & 255) << 18) | v, &bins[p1]);
    __builtin_nontemporal_store(((v & 255) << 18) | u, &bins[p2]);
}

// ---------------- phase 4: per-bucket CSR finalize + fused z0 init ---------------
__global__ void k_csr(const int* __restrict__ bins, const int* __restrict__ bktBase,
                      int N, int nU,
                      const float* __restrict__ ue, const float* __restrict__ ie,
                      int* __restrict__ row_ptr, int* __restrict__ cnt,
                      int* __restrict__ col, float* __restrict__ z0) {
    __shared__ int h[BROWS], s[BROWS], cur[BROWS];
    __shared__ float sInv[BROWS];
    int b = blockIdx.x, t = threadIdx.x;
    int base = bktBase[b];
    int n = bktBase[b + 1] - base;
    h[t] = 0;
    __syncthreads();
    for (int i = t; i < n; i += BROWS)
        atomicAdd(&h[bins[base + i] >> 18], 1);
    __syncthreads();
    int v = h[t];
    s[t] = v;
    __syncthreads();
    for (int o = 1; o < BROWS; o <<= 1) {
        int x = (t >= o) ? s[t - o] : 0;
        __syncthreads();
        s[t] += x;
        __syncthreads();
    }
    int excl = s[t] - v;
    int row = b * BROWS + t;
    if (row < N) {
        row_ptr[row] = base + excl;
        cnt[row] = v;
    }
    sInv[t] = (v > 0) ? (1.0f / sqrtf((float)v)) : 0.0f;
    cur[t] = excl;
    __syncthreads();
    // fused z0 = inv .* x0 for this bucket's 256 rows (16 rows per pass, coalesced)
    int rf = t & 15;            // float4 index within row
    int rg = t >> 4;            // row subgroup
    for (int pass = 0; pass < 16; pass++) {
        int r = pass * 16 + rg;
        int rr = b * BROWS + r;
        if (rr < N) {
            const float4* src = (rr < nU)
                ? ((const float4*)ue) + (size_t)rr * 16
                : ((const float4*)ie) + (size_t)(rr - nU) * 16;
            float4 val = src[rf];
            float sc = sInv[r];
            val.x *= sc; val.y *= sc; val.z *= sc; val.w *= sc;
            ((float4*)z0)[(size_t)rr * 16 + rf] = val;
        }
    }
    // placement
    for (int i = t; i < n; i += BROWS) {
        int p = bins[base + i];
        int pos = base + atomicAdd(&cur[p >> 18], 1);
        col[pos] = p & SRCMASK;
    }
}

// ---------------- SPMM + fused batch-accumulate tail -----------------------------
// Main blocks: 16-lane group per row (4 rows/wave), no cross-lane reduce.
// Tail blocks at layer l accumulate x_l = sqrt(deg)*z_l from the INPUT z (= zin).
// mode==0 (layer 0): acc = x0 read directly from ue/ie (covers deg==0 nodes);
// do NOT also add sqrt(deg)*z0 — that equals x0 and would double-count.
__global__ void k_spmm(const int* __restrict__ row_ptr, const int* __restrict__ col,
                       const float* __restrict__ x, float* __restrict__ y, int N,
                       int nBlkMain,
                       const int* __restrict__ users, const int* __restrict__ items,
                       int B, int nU, const int* __restrict__ cnt,
                       const float* __restrict__ ue, const float* __restrict__ ie,
                       float* __restrict__ acc, int mode) {
    int t = threadIdx.x;
    int grp = t >> 4, f4 = t & 15;
    const float4* x4 = (const float4*)x;
    if ((int)blockIdx.x < nBlkMain) {
        int row = blockIdx.x * 16 + grp;
        if (row >= N) return;
        int s = row_ptr[row], e = row_ptr[row + 1];
        float4 a0 = make_float4(0.f, 0.f, 0.f, 0.f);
        float4 a1 = make_float4(0.f, 0.f, 0.f, 0.f);
        int j = s;
        for (; j + 1 < e; j += 2) {
            int c0 = col[j];
            int c1 = col[j + 1];
            float4 v0 = x4[(size_t)c0 * 16 + f4];
            float4 v1 = x4[(size_t)c1 * 16 + f4];
            a0.x += v0.x; a0.y += v0.y; a0.z += v0.z; a0.w += v0.w;
            a1.x += v1.x; a1.y += v1.y; a1.z += v1.z; a1.w += v1.w;
        }
        if (j < e) {
            int c = col[j];
            float4 v = x4[(size_t)c * 16 + f4];
            a0.x += v.x; a0.y += v.y; a0.z += v.z; a0.w += v.w;
        }
        float rdeg = (e > s) ? (1.0f / (float)(e - s)) : 0.0f;
        a0.x = (a0.x + a1.x) * rdeg;
        a0.y = (a0.y + a1.y) * rdeg;
        a0.z = (a0.z + a1.z) * rdeg;
        a0.w = (a0.w + a1.w) * rdeg;
        ((float4*)y)[(size_t)row * 16 + f4] = a0;
    } else {
        int b = (blockIdx.x - nBlkMain) * 16 + grp;
        if (b >= 2 * B) return;
        float4 c;
        if (mode == 0) {
            // acc = x0 directly (correct for isolated nodes too)
            const float4* x0 = (b < B)
                ? ((const float4*)ue) + (size_t)users[b] * 16
                : ((const float4*)ie) + (size_t)items[b - B] * 16;
            c = x0[f4];
        } else {
            int row = (b < B) ? users[b] : (nU + items[b - B]);
            float f = sqrtf((float)cnt[row]);
            float4 v = x4[(size_t)row * 16 + f4];
            c = ((const float4*)acc)[(size_t)b * 16 + f4];
            c.x += f * v.x; c.y += f * v.y; c.z += f * v.z; c.w += f * v.w;
        }
        ((float4*)acc)[(size_t)b * 16 + f4] = c;
    }
}

// ---------------- final: add z4 term, then gamma[b] = dot(u,i)/25 ----------------
__global__ void k_dot(const float* __restrict__ acc, const float* __restrict__ z4,
                      const int* __restrict__ users, const int* __restrict__ items,
                      const int* __restrict__ cnt, int B, int nU,
                      float* __restrict__ out) {
    int b = blockIdx.x * (blockDim.x >> 6) + (threadIdx.x >> 6);
    int lane = threadIdx.x & 63;
    if (b >= B) return;
    int urow = users[b];
    int irow = nU + items[b];
    float fu = sqrtf((float)cnt[urow]);
    float fi = sqrtf((float)cnt[irow]);
    float au = acc[(size_t)b * 64 + lane]       + fu * z4[(size_t)urow * 64 + lane];
    float ai = acc[(size_t)(b + B) * 64 + lane] + fi * z4[(size_t)irow * 64 + lane];
    float p = au * ai;
    #pragma unroll
    for (int o = 32; o > 0; o >>= 1) p += __shfl_down(p, o, WAVE);
    if (lane == 0) out[b] = p * (1.0f / 25.0f);
}

extern "C" void kernel_launch(void* const* d_in, const int* in_sizes, int n_in,
                              void* d_out, int out_size, void* d_ws, size_t ws_size,
                              hipStream_t stream) {
    const int*   users = (const int*)d_in[0];
    const int*   items = (const int*)d_in[1];
    const int*   eu    = (const int*)d_in[2];
    const int*   ei    = (const int*)d_in[3];
    const float* ue    = (const float*)d_in[4];
    const float* ie    = (const float*)d_in[5];
    float* out = (float*)d_out;

    const int D  = 64;
    const int B  = in_sizes[0];
    const int nE = in_sizes[2];
    const int nU = in_sizes[4] / D;
    const int nI = in_sizes[5] / D;
    const int N  = nU + nI;
    const int nBkt = (N + BROWS - 1) / BROWS;   // 586 (<= NBKT_MAX required)
    const int total = 2 * nE;

    const int nBlkE = (nE + 255) / 256;         // 2344
    const int nJg   = (nBlkE + 7) / 8;          // 293
    const int nJ    = 8 * nJg;                  // 2344 here (== nBlkE -> no memset)

    // ---- carve workspace (256B-aligned chunks) ----
    char* p = (char*)d_ws;
    auto alloc = [&](size_t bytes) -> void* {
        void* r = (void*)p;
        p += (bytes + 255) & ~(size_t)255;
        return r;
    };
    int*   cntBB   = (int*)  alloc((size_t)nJ * nBkt * 4);     // 5.5 MB
    int*   baseBB  = (int*)  alloc((size_t)nBkt * nJ * 4);     // 5.5 MB
    int*   bktTot  = (int*)  alloc((size_t)nBkt * 4);
    int*   bktBase = (int*)  alloc((size_t)(nBkt + 1) * 4);
    int*   bins    = (int*)  alloc((size_t)total * 4);         // 4.8 MB packed
    int*   col     = (int*)  alloc((size_t)total * 4);         // 4.8 MB
    int*   row_ptr = (int*)  alloc((size_t)(N + 1) * 4);
    int*   cnt     = (int*)  alloc((size_t)N * 4);
    float* za      = (float*)alloc((size_t)N * D * 4);
    float* zb      = (float*)alloc((size_t)N * D * 4);
    float* acc     = (float*)alloc((size_t)2 * B * D * 4);

    // ---- build CSR: zero global atomics, fused z0 init ----
    if (nJ != nBlkE)
        hipMemsetAsync(cntBB, 0, (size_t)nJ * nBkt * 4, stream);
    k_hist<<<nBlkE, 256, 0, stream>>>(eu, ei, nE, nU, nBkt, nJg, cntBB);
    k_scanBkt<<<nBkt, 256, 0, stream>>>(cntBB, baseBB, bktTot, nBkt, nJ);
    k_scanTot<<<1, 1024, 0, stream>>>(bktTot, bktBase, row_ptr, nBkt, N, total);
    k_bin<<<nBlkE, 256, 0, stream>>>(eu, ei, nE, nU, nBkt, nJ, nJg, baseBB, bktBase, bins);
    k_csr<<<nBkt, BROWS, 0, stream>>>(bins, bktBase, N, nU, ue, ie,
                                      row_ptr, cnt, col, za);

    // ---- 4 propagation layers in z-space, batch-accumulate fused into tail ------
    const int nBlkMain = (N + 15) / 16;
    const int nBlkTail = (2 * B + 15) / 16;
    float* zin = za;
    float* zout = zb;
    for (int l = 0; l < 4; l++) {
        k_spmm<<<nBlkMain + nBlkTail, 256, 0, stream>>>(
            row_ptr, col, zin, zout, N, nBlkMain,
            users, items, B, nU, cnt, ue, ie, acc, (l == 0) ? 0 : 1);
        float* t = zin; zin = zout; zout = t;
    }

    // ---- final: z4 term + dot ----
    k_dot<<<(B + 3) / 4, 256, 0, stream>>>(acc, zin, users, items, cnt, B, nU, out);
}